// Round 1
// baseline (198.218 us; speedup 1.0000x reference)
//
#include <hip/hip_runtime.h>
#include <cstdint>
#include <cstddef>

#define NB_B    1024
#define NPAIRS  28
#define NOUT    23      // col0 = indeterminate logit, 1..5 lr, 6..8 cr, 9..22 mr
#define WPITCH  24

// ws layout (float offsets)
#define WS_WBIG 0            // 3072*24 = 73728
#define WS_BMAT 73728        // 640*24  = 15360
#define WS_BBIG 89088        // 24
#define WS_ND   89728        // ncn*8192*23
// ED follows ND

// output offsets (floats)
#define OUT_IND 0
#define OUT_LAB 28672
#define OUT_LRP 57344
#define OUT_CRP 98304
#define OUT_MRP 122880
#define OUT_LRN 237568
#define OUT_CRN 339968
#define OUT_MRN 401408

__device__ __constant__ int d_pi[28] = {0,0,0,0,0,0,0,1,1,1,1,1,1,2,2,2,2,2,3,3,3,3,4,4,4,5,5,6};
__device__ __constant__ int d_pj[28] = {1,2,3,4,5,6,7,2,3,4,5,6,7,3,4,5,6,7,4,5,6,7,5,6,7,6,7,7};

__device__ __forceinline__ float wh_at(const float* wlr, const float* wcr, const float* wmr,
                                       int j, int h) {
  return (h < 5) ? wlr[j*5 + h] : (h < 8) ? wcr[j*3 + (h-5)] : wmr[j*14 + (h-8)];
}

// ---------------- prep_a: Bmat = [T1(128x24); WhE(512x24)], b_big ----------------
// T1[m][0] = W_ind2[m]; T1[m][1+h] = sum_j W_rel[3072+m][j] * Wh[j][h]
// WhE[j][0] = 0; WhE[j][1+h] = Wh[j][h]
// b_big[0] = b_ind1.W_ind2 + b_ind2 ; b_big[1+h] = (b_rel + b_ind1@W_rel2).Wh[:,h] + bh[h]
__global__ __launch_bounds__(256) void prep_a(
    const float* __restrict__ w_rel, const float* __restrict__ w_ind2,
    const float* __restrict__ w_lr, const float* __restrict__ w_cr, const float* __restrict__ w_mr,
    const float* __restrict__ b_ind1, const float* __restrict__ b_ind2,
    const float* __restrict__ b_rel,
    const float* __restrict__ b_lr, const float* __restrict__ b_cr, const float* __restrict__ b_mr,
    float* __restrict__ bmat, float* __restrict__ bbig) {
  int bid = blockIdx.x, tid = threadIdx.x;
  if (bid == 0) {
    __shared__ float sbrel[512];
    for (int j = tid; j < 512; j += 256) {
      float a = b_rel[j];
      for (int m = 0; m < 128; ++m)
        a = fmaf(b_ind1[m], w_rel[(size_t)(3072 + m)*512 + j], a);
      sbrel[j] = a;
    }
    __syncthreads();
    if (tid < 22) {
      int h = tid;
      float bh = (h < 5) ? b_lr[h] : (h < 8) ? b_cr[h-5] : b_mr[h-8];
      float a = bh;
      for (int j = 0; j < 512; ++j)
        a = fmaf(sbrel[j], wh_at(w_lr, w_cr, w_mr, j, h), a);
      bbig[1 + h] = a;
    } else if (tid == 22) {
      float a = b_ind2[0];
      for (int m = 0; m < 128; ++m) a = fmaf(b_ind1[m], w_ind2[m], a);
      bbig[0] = a;
    } else if (tid == 23) {
      bbig[23] = 0.f;
    }
  } else if (bid < 13) {               // T1: 128*24 = 3072 slots
    int g = (bid - 1)*256 + tid;
    int m = g / 24, n = g % 24;
    float val;
    if (n == 0) val = w_ind2[m];
    else if (n == 23) val = 0.f;
    else {
      int h = n - 1;
      float a = 0.f;
      const float* wr2 = w_rel + (size_t)(3072 + m)*512;
      for (int j = 0; j < 512; ++j)
        a = fmaf(wr2[j], wh_at(w_lr, w_cr, w_mr, j, h), a);
      val = a;
    }
    bmat[m*24 + n] = val;
  } else {                             // WhE: 512*24 = 12288 slots, blocks 13..60
    int idx = (bid - 13)*256 + tid;
    if (idx < 512*24) {
      int j = idx / 24, n = idx % 24;
      float val = (n >= 1 && n <= 22) ? wh_at(w_lr, w_cr, w_mr, j, n - 1) : 0.f;
      bmat[(128 + j)*24 + n] = val;
    }
  }
}

// ---------------- prep_b: W_big[k][n] = sum_i W_ind1[k][i]*Bmat[i][n] + sum_j W_rel[k][j]*Bmat[128+j][n]
__global__ __launch_bounds__(256) void prep_b(
    const float* __restrict__ w_ind1, const float* __restrict__ w_rel,
    const float* __restrict__ bmat, float* __restrict__ wbig) {
  int g = blockIdx.x*256 + threadIdx.x;      // 3072*24 = 73728 exactly
  int k = g / 24, n = g % 24;
  if (n == 23) { wbig[g] = 0.f; return; }
  float a = 0.f;
  const float* w1 = w_ind1 + (size_t)k*128;
  for (int i = 0; i < 128; ++i) a = fmaf(w1[i], bmat[i*24 + n], a);
  const float* wr = w_rel + (size_t)k*512;
  for (int j = 0; j < 512; ++j) a = fmaf(wr[j], bmat[(128 + j)*24 + n], a);
  wbig[g] = a;
}

// ---------------- main: partial dot-products, lane=row, uniform-k, W via scalar loads
__global__ __launch_bounds__(256) void kmain(
    const float* __restrict__ nf, const float* __restrict__ intf,
    const float* __restrict__ wbig, float* __restrict__ ndp, float* __restrict__ edp,
    int ncn, int nce) {
  __shared__ float4 tile[4][512];            // 8KB per wave
  int tid = threadIdx.x;
  int l = tid & 63;
  int w = __builtin_amdgcn_readfirstlane(tid >> 6);
  int bid = blockIdx.x;
  int nodeBlocks = 32*ncn;
  bool isNode = bid < nodeBlocks;

  int chunk, nsub, R0, kd0;
  const float* wb;
  float* outp;
  if (isNode) {
    chunk = bid % ncn; int rg = bid / ncn;
    int KC = 2048/ncn; kd0 = chunk*KC; nsub = KC/32;
    wb = wbig + (size_t)kd0*WPITCH;
    outp = ndp + (size_t)chunk*8192*23;
    R0 = rg*256 + w*64;
  } else {
    int eb = bid - nodeBlocks;
    chunk = eb % nce; int rg = eb / nce;
    int KC = 1024/nce; kd0 = chunk*KC; nsub = KC/32;
    wb = wbig + (size_t)(2048 + kd0)*WPITCH;
    outp = edp + (size_t)chunk*28672*23;
    R0 = rg*256 + w*64;
  }

  int lg = l >> 3, f0 = l & 7;
  int fs = f0 ^ lg;
  const float* bases[8];
#pragma unroll
  for (int q = 0; q < 8; ++q) {
    int row = R0 + q*8 + lg;
    const float* rp;
    if (isNode) rp = nf + (size_t)row*2048;
    else {
      int b = row / 28, p = row % 28;
      rp = intf + (size_t)(b*64 + d_pi[p]*8 + d_pj[p])*1024;
    }
    bases[q] = rp + kd0;
  }

  float acc[23];
#pragma unroll
  for (int n = 0; n < 23; ++n) acc[n] = 0.f;
  float4* tw = &tile[w][0];

  for (int ss = 0; ss < nsub; ++ss) {
    float4 v[8];
#pragma unroll
    for (int q = 0; q < 8; ++q)
      v[q] = *(((const float4*)bases[q]) + (ss*8 + f0));
#pragma unroll
    for (int q = 0; q < 8; ++q)
      tw[(q*8 + lg)*8 + fs] = v[q];
    asm volatile("s_waitcnt lgkmcnt(0)" ::: "memory");
    __builtin_amdgcn_sched_barrier(0);

    const float* wrbase = wb + (size_t)ss*32*WPITCH;
#pragma unroll
    for (int k4 = 0; k4 < 8; ++k4) {
      float4 x = tw[l*8 + (k4 ^ f0)];
      const float* wr = wrbase + k4*4*WPITCH;
#pragma unroll
      for (int s = 0; s < 4; ++s) {
        float xs = (s == 0) ? x.x : (s == 1) ? x.y : (s == 2) ? x.z : x.w;
#pragma unroll
        for (int n = 0; n < 23; ++n)
          acc[n] = fmaf(xs, wr[s*WPITCH + n], acc[n]);
      }
    }
    asm volatile("" ::: "memory");
    __builtin_amdgcn_sched_barrier(0);
  }

  // transpose through per-wave LDS region, then coalesced partial store
  float* t = (float*)tw;
#pragma unroll
  for (int n = 0; n < 23; ++n) t[l*24 + n] = acc[n];
  asm volatile("s_waitcnt lgkmcnt(0)" ::: "memory");
  __builtin_amdgcn_sched_barrier(0);
  float* op = outp + (size_t)R0*23;
  for (int g = l; g < 64*23; g += 64)
    op[g] = t[(g/23)*24 + (g%23)];
}

// ---------------- combine: sum partials, bias, sigmoid, label, pos/neg scatter
__global__ __launch_bounds__(256) void kcombine(
    const float* __restrict__ ndp, const float* __restrict__ edp,
    const float* __restrict__ bbig, const int* __restrict__ opairs,
    float* __restrict__ out, int ncn, int nce) {
  __shared__ float snd[8*23];
  __shared__ int spos[8];
  int tid = threadIdx.x;
  for (int i = 0; i < 4; ++i) {
    int b = blockIdx.x*4 + i;
    if (tid < 184) {
      int o = tid / 23, n = tid % 23;
      float s = 0.f;
      for (int c = 0; c < ncn; ++c)
        s += ndp[((size_t)c*8192 + b*8 + o)*23 + n];
      snd[tid] = s;
    } else if (tid < 192) {
      int r = tid - 184;
      int oi = opairs[b*16 + r*2], oj = opairs[b*16 + r*2 + 1];
      int a = min(oi, oj), bb = max(oi, oj);
      spos[r] = 7*a - (a*(a+1))/2 + bb - 1;
    }
    __syncthreads();
    for (int g = tid; g < 644; g += 256) {
      int p = g / 23, n = g % 23;
      float ed = 0.f;
      for (int c = 0; c < nce; ++c)
        ed += edp[((size_t)c*28672 + b*28 + p)*23 + n];
      float val = 0.5f*(snd[d_pi[p]*23 + n] + snd[d_pj[p]*23 + n]) + ed + bbig[n];
      int slot = -1, below = 0;
#pragma unroll
      for (int r = 0; r < 8; ++r) {
        int pl = spos[r];
        slot = (pl == p) ? r : slot;
        below += (pl < p) ? 1 : 0;
      }
      if (n == 0) {
        out[OUT_IND + b*28 + p] = 1.f/(1.f + expf(-val));
        out[OUT_LAB + b*28 + p] = (slot >= 0) ? 1.f : 0.f;
      } else {
        int h = n - 1;
        if (slot >= 0) {
          int rr = b*8 + slot;
          if (h < 5)      out[OUT_LRP + rr*5  + h]     = val;
          else if (h < 8) out[OUT_CRP + rr*3  + (h-5)] = val;
          else            out[OUT_MRP + rr*14 + (h-8)] = val;
        } else {
          int s = p - below;
          int rr = b*20 + s;
          if (h < 5)      out[OUT_LRN + rr*5  + h]     = val;
          else if (h < 8) out[OUT_CRN + rr*3  + (h-5)] = val;
          else            out[OUT_MRN + rr*14 + (h-8)] = val;
        }
      }
    }
    __syncthreads();
  }
}

extern "C" void kernel_launch(void* const* d_in, const int* in_sizes, int n_in,
                              void* d_out, int out_size, void* d_ws, size_t ws_size,
                              hipStream_t stream) {
  const float* nf     = (const float*)d_in[0];
  const float* intf   = (const float*)d_in[1];
  const int*   opairs = (const int*)d_in[2];
  const float* w_ind1 = (const float*)d_in[3];
  const float* b_ind1 = (const float*)d_in[4];
  const float* w_ind2 = (const float*)d_in[5];
  const float* b_ind2 = (const float*)d_in[6];
  const float* w_rel  = (const float*)d_in[7];
  const float* b_rel  = (const float*)d_in[8];
  const float* w_cr   = (const float*)d_in[9];
  const float* b_cr   = (const float*)d_in[10];
  const float* w_lr   = (const float*)d_in[11];
  const float* b_lr   = (const float*)d_in[12];
  const float* w_mr   = (const float*)d_in[13];
  const float* b_mr   = (const float*)d_in[14];
  float* out = (float*)d_out;
  float* ws  = (float*)d_ws;

  auto needBytes = [](int a, int b) {
    return (size_t)(WS_ND + (size_t)a*8192*23 + (size_t)b*28672*23)*4;
  };
  int ncn, nce;
  if      (ws_size >= needBytes(8, 4)) { ncn = 8; nce = 4; }
  else if (ws_size >= needBytes(4, 2)) { ncn = 4; nce = 2; }
  else                                 { ncn = 2; nce = 1; }

  float* wbig = ws + WS_WBIG;
  float* bmat = ws + WS_BMAT;
  float* bbig = ws + WS_BBIG;
  float* ndp  = ws + WS_ND;
  float* edp  = ndp + (size_t)ncn*8192*23;

  prep_a<<<61, 256, 0, stream>>>(w_rel, w_ind2, w_lr, w_cr, w_mr,
                                 b_ind1, b_ind2, b_rel, b_lr, b_cr, b_mr, bmat, bbig);
  prep_b<<<288, 256, 0, stream>>>(w_ind1, w_rel, bmat, wbig);
  kmain<<<32*ncn + 112*nce, 256, 0, stream>>>(nf, intf, wbig, ndp, edp, ncn, nce);
  kcombine<<<256, 256, 0, stream>>>(ndp, edp, bbig, opairs, out, ncn, nce);
}